// Round 5
// baseline (208.695 us; speedup 1.0000x reference)
//
#include <hip/hip_runtime.h>
#include <hip/hip_bf16.h>

typedef __attribute__((ext_vector_type(8))) short short8;
typedef __attribute__((ext_vector_type(4))) float f32x4;
typedef __attribute__((ext_vector_type(16))) float f32x16;
typedef __attribute__((ext_vector_type(2))) int int2v;

#define N_TOK 8192
#define D_HALF 64
#define D_FULL 128
#define QW 32                     // q rows per block (one 32-col MFMA tile)
#define KT 64                     // keys per inner iteration
#define KSPL 16                   // waves per block = k-split
#define KEYS_PER (N_TOK / KSPL)   // 512
#define NT (KEYS_PER / KT)        // 8
#define OSTR 132                  // padded LDS row stride (floats)
#define THR 8.0f

__global__ __launch_bounds__(256) void precompute_kernel(
    const float* __restrict__ mag, const float* __restrict__ phase,
    __hip_bfloat16* __restrict__ Q, __hip_bfloat16* __restrict__ Vt)
{
    int idx = blockIdx.x * 256 + threadIdx.x;
    if (idx >= N_TOK * D_HALF) return;
    int n = idx >> 6, d = idx & 63;
    float m = mag[idx], p = phase[idx];
    float s, c;
    sincosf(p, &s, &c);
    Q[(size_t)n * D_FULL + d]          = __float2bfloat16(m * c);
    Q[(size_t)n * D_FULL + D_HALF + d] = __float2bfloat16(m * s);
    Vt[(size_t)d * N_TOK + n]            = __float2bfloat16(m);
    Vt[(size_t)(D_HALF + d) * N_TOK + n] = __float2bfloat16(p);
}

static __device__ __forceinline__ unsigned bfpair(float lo, float hi)
{
    __hip_bfloat16 l = __float2bfloat16(lo), h = __float2bfloat16(hi);
    unsigned short ul = *reinterpret_cast<unsigned short*>(&l);
    unsigned short uh = *reinterpret_cast<unsigned short*>(&h);
    return (unsigned)ul | ((unsigned)uh << 16);
}

// 1024 threads = 16 waves per block, 1 block/CU -> 4 waves/SIMD.
// All waves share the block's 32 q rows; each owns 1/16 of the keys.
// Swapped-operand 32x32x16 MFMA keeps softmax state fully lane-local.
__global__ __launch_bounds__(1024, 1) void attn_kernel(
    const __hip_bfloat16* __restrict__ Q, const __hip_bfloat16* __restrict__ Vt,
    float* __restrict__ out)
{
    __shared__ __align__(16) float O_lds[8][QW][OSTR];   // 135168 B (merge slots)
    __shared__ float ms_lds[8][2][QW];                   // 2 KB

    const int tid  = threadIdx.x;
    const int wid  = tid >> 6;    // 0..15
    const int lane = tid & 63;
    const int li   = lane & 31;   // q column (QK^T) / d row (PV)
    const int hi   = lane >> 5;

    const int qbase = blockIdx.x * QW;
    const int k0    = wid * KEYS_PER;

    // Q as B-operand: col = li (q row), k = d = ks*16 + 8*hi + i
    short8 bq[8];
    {
        const __hip_bfloat16* qp = Q + (size_t)(qbase + li) * D_FULL + 8 * hi;
        #pragma unroll
        for (int ks = 0; ks < 8; ++ks)
            bq[ks] = *reinterpret_cast<const short8*>(qp + ks * 16);
    }

    f32x16 acc[4];   // O^T: acc[dblk], col = q = li, row = d-offset
    #pragma unroll
    for (int d = 0; d < 4; ++d) acc[d] = (f32x16)(0.0f);
    float mrow = -3.0e38f, srow = 0.0f;

    for (int t = 0; t < NT; ++t) {
        const int kt = k0 + t * KT;

        // ---- S^T = K . Q : two 32x32 key-subtiles ----
        f32x16 st[2];
        __builtin_amdgcn_s_setprio(1);
        #pragma unroll
        for (int ksub = 0; ksub < 2; ++ksub) {
            st[ksub] = (f32x16)(0.0f);
            const __hip_bfloat16* kp = Q + (size_t)(kt + ksub * 32 + li) * D_FULL + 8 * hi;
            #pragma unroll
            for (int ks = 0; ks < 8; ++ks) {
                short8 kf = *reinterpret_cast<const short8*>(kp + ks * 16);
                st[ksub] = __builtin_amdgcn_mfma_f32_32x32x16_bf16(kf, bq[ks], st[ksub], 0, 0, 0);
            }
        }
        __builtin_amdgcn_s_setprio(0);

        // ---- online softmax, lane-local (q = li; 32 of 64 keys here, rest on lane^32)
        float mx[16];
        #pragma unroll
        for (int r = 0; r < 16; ++r) mx[r] = fmaxf(st[0][r], st[1][r]);
        #pragma unroll
        for (int w = 8; w >= 1; w >>= 1)
            #pragma unroll
            for (int r = 0; r < w; ++r) mx[r] = fmaxf(mx[r], mx[r + w]);
        float pmax = fmaxf(mx[0], __shfl_xor(mx[0], 32));

        if (!__all(pmax - mrow <= THR)) {          // defer-max: rarely taken
            float mn  = fmaxf(mrow, pmax);
            float scl = __expf(mrow - mn);
            srow *= scl;
            #pragma unroll
            for (int d = 0; d < 4; ++d)
                #pragma unroll
                for (int r = 0; r < 16; ++r) acc[d][r] *= scl;
            mrow = mn;
        }

        #pragma unroll
        for (int ksub = 0; ksub < 2; ++ksub)
            #pragma unroll
            for (int r = 0; r < 16; ++r)
                st[ksub][r] = __expf(st[ksub][r] - mrow);

        float sm[16];
        #pragma unroll
        for (int r = 0; r < 16; ++r) sm[r] = st[0][r] + st[1][r];
        #pragma unroll
        for (int w = 8; w >= 1; w >>= 1)
            #pragma unroll
            for (int r = 0; r < w; ++r) sm[r] += sm[r + w];
        srow += sm[0] + __shfl_xor(sm[0], 32);

        // ---- PV: O^T += V^T . P, P repacked in-register via permlane32_swap ----
        // u.w[0]={a0.lo,b0.lo}, u.w[2]={a0.hi,b0.hi} -> swap(dst=a0, src=b0); ditto (a1,b1)
        #pragma unroll
        for (int c = 0; c < 4; ++c) {
            const f32x16& P = st[c >> 1];
            const int b = 8 * (c & 1);
            unsigned a0 = bfpair(P[b + 0], P[b + 1]);
            unsigned a1 = bfpair(P[b + 2], P[b + 3]);
            unsigned b0 = bfpair(P[b + 4], P[b + 5]);
            unsigned b1 = bfpair(P[b + 6], P[b + 7]);
            int2v r0 = __builtin_amdgcn_permlane32_swap((int)a0, (int)b0, false, false);
            int2v r1 = __builtin_amdgcn_permlane32_swap((int)a1, (int)b1, false, false);
            union { int w[4]; short8 v; } u;
            u.w[0] = r0[0]; u.w[1] = r1[0]; u.w[2] = r0[1]; u.w[3] = r1[1];

            const __hip_bfloat16* vp = Vt + (size_t)li * N_TOK + kt + c * 16 + 8 * hi;
            __builtin_amdgcn_s_setprio(1);
            #pragma unroll
            for (int d = 0; d < 4; ++d) {
                short8 vf = *reinterpret_cast<const short8*>(vp + (size_t)d * 32 * N_TOK);
                acc[d] = __builtin_amdgcn_mfma_f32_32x32x16_bf16(vf, u.v, acc[d], 0, 0, 0);
            }
            __builtin_amdgcn_s_setprio(0);
        }
    }

    // ---- k-split merge: 16 partials -> 8 -> parallel 8-way final ----
    auto store_partial = [&](int slot) {
        #pragma unroll
        for (int d = 0; d < 4; ++d)
            #pragma unroll
            for (int rr = 0; rr < 4; ++rr) {
                f32x4 v;
                #pragma unroll
                for (int j = 0; j < 4; ++j) v[j] = acc[d][4 * rr + j];
                *reinterpret_cast<f32x4*>(&O_lds[slot][li][d * 32 + 8 * rr + 4 * hi]) = v;
            }
        if (hi == 0) { ms_lds[slot][0][li] = mrow; ms_lds[slot][1][li] = srow; }
    };
    auto merge_partial = [&](int slot) {
        float mb = ms_lds[slot][0][li], sb = ms_lds[slot][1][li];
        float M  = fmaxf(mrow, mb);
        float ea = __expf(mrow - M), eb = __expf(mb - M);
        srow = srow * ea + sb * eb;
        mrow = M;
        #pragma unroll
        for (int d = 0; d < 4; ++d)
            #pragma unroll
            for (int rr = 0; rr < 4; ++rr) {
                f32x4 v = *reinterpret_cast<const f32x4*>(&O_lds[slot][li][d * 32 + 8 * rr + 4 * hi]);
                #pragma unroll
                for (int j = 0; j < 4; ++j)
                    acc[d][4 * rr + j] = acc[d][4 * rr + j] * ea + v[j] * eb;
            }
    };

    __syncthreads();
    if (wid >= 8) store_partial(wid - 8);
    __syncthreads();
    if (wid < 8) merge_partial(wid);
    __syncthreads();
    if (wid < 8) store_partial(wid);
    __syncthreads();

    // ---- final 8-way merge + write; thread -> (q, 4 d's) ----
    {
        int q  = tid >> 5;                 // 0..31
        int dg = (tid & 31) * 4;           // 0..124
        float M = ms_lds[0][0][q];
        #pragma unroll
        for (int s = 1; s < 8; ++s) M = fmaxf(M, ms_lds[s][0][q]);
        float e[8], S = 0.0f;
        #pragma unroll
        for (int s = 0; s < 8; ++s) {
            e[s] = __expf(ms_lds[s][0][q] - M);
            S += ms_lds[s][1][q] * e[s];
        }
        float inv = 1.0f / S;
        f32x4 o = (f32x4)(0.0f);
        #pragma unroll
        for (int s = 0; s < 8; ++s) {
            f32x4 u = *reinterpret_cast<const f32x4*>(&O_lds[s][q][dg]);
            #pragma unroll
            for (int j = 0; j < 4; ++j) o[j] += u[j] * e[s];
        }
        #pragma unroll
        for (int j = 0; j < 4; ++j) o[j] *= inv;
        int row = qbase + q;
        float* dst = (dg < D_HALF)
            ? out + (size_t)row * D_HALF + dg
            : out + (size_t)N_TOK * D_HALF + (size_t)row * D_HALF + (dg - D_HALF);
        *reinterpret_cast<f32x4*>(dst) = o;
    }
}

extern "C" void kernel_launch(void* const* d_in, const int* in_sizes, int n_in,
                              void* d_out, int out_size, void* d_ws, size_t ws_size,
                              hipStream_t stream)
{
    const float* mag   = (const float*)d_in[0];
    const float* phase = (const float*)d_in[1];
    float* out = (float*)d_out;

    __hip_bfloat16* Q  = (__hip_bfloat16*)d_ws;                  // 2 MB
    __hip_bfloat16* Vt = Q + (size_t)N_TOK * D_FULL;             // 2 MB

    precompute_kernel<<<(N_TOK * D_HALF + 255) / 256, 256, 0, stream>>>(mag, phase, Q, Vt);
    attn_kernel<<<N_TOK / QW, 1024, 0, stream>>>(Q, Vt, out);
}

// Round 6
// 138.767 us; speedup vs baseline: 1.5039x; 1.5039x over previous
//
#include <hip/hip_runtime.h>
#include <hip/hip_bf16.h>

typedef __attribute__((ext_vector_type(8))) short short8;
typedef __attribute__((ext_vector_type(4))) float f32x4;
typedef __attribute__((ext_vector_type(16))) float f32x16;
typedef __attribute__((ext_vector_type(2))) int int2v;

#define N_TOK 8192
#define D_HALF 64
#define D_FULL 128
#define QW 32                     // q rows per block (one 32-col MFMA tile)
#define KT 64                     // keys per inner iteration
#define NWAVE 12                  // waves per block (uneven k-split)
#define TILES_TOT (N_TOK / KT)    // 128
#define OSTR 132                  // padded LDS row stride (floats)
#define THR 8.0f

__global__ __launch_bounds__(256) void precompute_kernel(
    const float* __restrict__ mag, const float* __restrict__ phase,
    __hip_bfloat16* __restrict__ Q, __hip_bfloat16* __restrict__ Vt)
{
    int idx = blockIdx.x * 256 + threadIdx.x;
    if (idx >= N_TOK * D_HALF) return;
    int n = idx >> 6, d = idx & 63;
    float m = mag[idx], p = phase[idx];
    float s, c;
    sincosf(p, &s, &c);
    Q[(size_t)n * D_FULL + d]          = __float2bfloat16(m * c);
    Q[(size_t)n * D_FULL + D_HALF + d] = __float2bfloat16(m * s);
    Vt[(size_t)d * N_TOK + n]            = __float2bfloat16(m);
    Vt[(size_t)(D_HALF + d) * N_TOK + n] = __float2bfloat16(p);
}

static __device__ __forceinline__ unsigned bfpair(float lo, float hi)
{
    __hip_bfloat16 l = __float2bfloat16(lo), h = __float2bfloat16(hi);
    unsigned short ul = *reinterpret_cast<unsigned short*>(&l);
    unsigned short uh = *reinterpret_cast<unsigned short*>(&h);
    return (unsigned)ul | ((unsigned)uh << 16);
}

// 768 threads = 12 waves, 1 block/CU -> 3 waves/SIMD (the max the ~164-reg
// wave state allows without spilling; round-5 showed 4/SIMD spills).
// All waves share the block's 32 q rows; keys split 12-ways (uneven tiles).
__global__ __launch_bounds__(768, 3) void attn_kernel(
    const __hip_bfloat16* __restrict__ Q, const __hip_bfloat16* __restrict__ Vt,
    float* __restrict__ out)
{
    __shared__ __align__(16) float O_lds[6][QW][OSTR];   // 101376 B (merge slots)
    __shared__ float ms_lds[6][2][QW];                   // 1536 B

    const int tid  = threadIdx.x;
    const int wid  = tid >> 6;    // 0..11
    const int lane = tid & 63;
    const int li   = lane & 31;   // q column (QK^T) / d row (PV)
    const int hi   = lane >> 5;

    const int qbase = blockIdx.x * QW;
    // uneven split of 128 tiles over 12 waves: waves 0-7 get 11, 8-11 get 10
    const int t_start = (wid < 8) ? 11 * wid : 88 + 10 * (wid - 8);
    const int t_count = (wid < 8) ? 11 : 10;

    // Q as B-operand: col = li (q row), k = d = ks*16 + 8*hi + i
    short8 bq[8];
    {
        const __hip_bfloat16* qp = Q + (size_t)(qbase + li) * D_FULL + 8 * hi;
        #pragma unroll
        for (int ks = 0; ks < 8; ++ks)
            bq[ks] = *reinterpret_cast<const short8*>(qp + ks * 16);
    }

    f32x16 acc[4];   // O^T: acc[dblk], col = q = li, row = d-offset
    #pragma unroll
    for (int d = 0; d < 4; ++d) acc[d] = (f32x16)(0.0f);
    float mrow = -3.0e38f, srow = 0.0f;

    for (int t = 0; t < t_count; ++t) {
        const int kt = (t_start + t) * KT;

        // ---- S^T = K . Q : two 32x32 key-subtiles ----
        f32x16 st[2];
        __builtin_amdgcn_s_setprio(1);
        #pragma unroll
        for (int ksub = 0; ksub < 2; ++ksub) {
            st[ksub] = (f32x16)(0.0f);
            const __hip_bfloat16* kp = Q + (size_t)(kt + ksub * 32 + li) * D_FULL + 8 * hi;
            #pragma unroll
            for (int ks = 0; ks < 8; ++ks) {
                short8 kf = *reinterpret_cast<const short8*>(kp + ks * 16);
                st[ksub] = __builtin_amdgcn_mfma_f32_32x32x16_bf16(kf, bq[ks], st[ksub], 0, 0, 0);
            }
        }
        __builtin_amdgcn_s_setprio(0);

        // ---- online softmax, lane-local (q = li; 32 of 64 keys here, rest on lane^32)
        float mx[16];
        #pragma unroll
        for (int r = 0; r < 16; ++r) mx[r] = fmaxf(st[0][r], st[1][r]);
        #pragma unroll
        for (int w = 8; w >= 1; w >>= 1)
            #pragma unroll
            for (int r = 0; r < w; ++r) mx[r] = fmaxf(mx[r], mx[r + w]);
        float pmax = fmaxf(mx[0], __shfl_xor(mx[0], 32));

        if (!__all(pmax - mrow <= THR)) {          // defer-max: rarely taken
            float mn  = fmaxf(mrow, pmax);
            float scl = __expf(mrow - mn);
            srow *= scl;
            #pragma unroll
            for (int d = 0; d < 4; ++d)
                #pragma unroll
                for (int r = 0; r < 16; ++r) acc[d][r] *= scl;
            mrow = mn;
        }

        #pragma unroll
        for (int ksub = 0; ksub < 2; ++ksub)
            #pragma unroll
            for (int r = 0; r < 16; ++r)
                st[ksub][r] = __expf(st[ksub][r] - mrow);

        float sm[16];
        #pragma unroll
        for (int r = 0; r < 16; ++r) sm[r] = st[0][r] + st[1][r];
        #pragma unroll
        for (int w = 8; w >= 1; w >>= 1)
            #pragma unroll
            for (int r = 0; r < w; ++r) sm[r] += sm[r + w];
        srow += sm[0] + __shfl_xor(sm[0], 32);

        // ---- PV: O^T += V^T . P, P repacked in-register via permlane32_swap ----
        // u.w[0]={a0.lo,b0.lo}, u.w[2]={a0.hi,b0.hi} -> swap(dst=a0, src=b0); ditto (a1,b1)
        #pragma unroll
        for (int c = 0; c < 4; ++c) {
            const f32x16& P = st[c >> 1];
            const int b = 8 * (c & 1);
            unsigned a0 = bfpair(P[b + 0], P[b + 1]);
            unsigned a1 = bfpair(P[b + 2], P[b + 3]);
            unsigned b0 = bfpair(P[b + 4], P[b + 5]);
            unsigned b1 = bfpair(P[b + 6], P[b + 7]);
            int2v r0 = __builtin_amdgcn_permlane32_swap((int)a0, (int)b0, false, false);
            int2v r1 = __builtin_amdgcn_permlane32_swap((int)a1, (int)b1, false, false);
            union { int w[4]; short8 v; } u;
            u.w[0] = r0[0]; u.w[1] = r1[0]; u.w[2] = r0[1]; u.w[3] = r1[1];

            const __hip_bfloat16* vp = Vt + (size_t)li * N_TOK + kt + c * 16 + 8 * hi;
            __builtin_amdgcn_s_setprio(1);
            #pragma unroll
            for (int d = 0; d < 4; ++d) {
                short8 vf = *reinterpret_cast<const short8*>(vp + (size_t)d * 32 * N_TOK);
                acc[d] = __builtin_amdgcn_mfma_f32_32x32x16_bf16(vf, u.v, acc[d], 0, 0, 0);
            }
            __builtin_amdgcn_s_setprio(0);
        }
    }

    // ---- k-split merge: 12 partials -> 6 -> 3 -> parallel 3-way final ----
    auto store_partial = [&](int slot) {
        #pragma unroll
        for (int d = 0; d < 4; ++d)
            #pragma unroll
            for (int rr = 0; rr < 4; ++rr) {
                f32x4 v;
                #pragma unroll
                for (int j = 0; j < 4; ++j) v[j] = acc[d][4 * rr + j];
                *reinterpret_cast<f32x4*>(&O_lds[slot][li][d * 32 + 8 * rr + 4 * hi]) = v;
            }
        if (hi == 0) { ms_lds[slot][0][li] = mrow; ms_lds[slot][1][li] = srow; }
    };
    auto merge_partial = [&](int slot) {
        float mb = ms_lds[slot][0][li], sb = ms_lds[slot][1][li];
        float M  = fmaxf(mrow, mb);
        float ea = __expf(mrow - M), eb = __expf(mb - M);
        srow = srow * ea + sb * eb;
        mrow = M;
        #pragma unroll
        for (int d = 0; d < 4; ++d)
            #pragma unroll
            for (int rr = 0; rr < 4; ++rr) {
                f32x4 v = *reinterpret_cast<const f32x4*>(&O_lds[slot][li][d * 32 + 8 * rr + 4 * hi]);
                #pragma unroll
                for (int j = 0; j < 4; ++j)
                    acc[d][4 * rr + j] = acc[d][4 * rr + j] * ea + v[j] * eb;
            }
    };

    __syncthreads();
    if (wid >= 6) store_partial(wid - 6);      // waves 6-11 -> slots 0-5
    __syncthreads();
    if (wid < 6) merge_partial(wid);           // waves 0-5 absorb
    __syncthreads();
    if (wid >= 3 && wid < 6) store_partial(wid - 3);  // waves 3-5 -> slots 0-2
    __syncthreads();
    if (wid < 3) merge_partial(wid);           // waves 0-2 absorb
    __syncthreads();
    if (wid < 3) store_partial(wid);           // final 3 partials -> slots 0-2
    __syncthreads();

    // ---- final 3-way merge + write; f32x4 chunks strided over 768 threads ----
    for (int i = tid; i < QW * D_FULL / 4; i += 768) {
        int q  = i >> 5;                 // 0..31
        int dg = (i & 31) * 4;           // 0..124
        float M = fmaxf(fmaxf(ms_lds[0][0][q], ms_lds[1][0][q]), ms_lds[2][0][q]);
        float e[3], S = 0.0f;
        #pragma unroll
        for (int s = 0; s < 3; ++s) {
            e[s] = __expf(ms_lds[s][0][q] - M);
            S += ms_lds[s][1][q] * e[s];
        }
        float inv = 1.0f / S;
        f32x4 o = (f32x4)(0.0f);
        #pragma unroll
        for (int s = 0; s < 3; ++s) {
            f32x4 u = *reinterpret_cast<const f32x4*>(&O_lds[s][q][dg]);
            #pragma unroll
            for (int j = 0; j < 4; ++j) o[j] += u[j] * e[s];
        }
        #pragma unroll
        for (int j = 0; j < 4; ++j) o[j] *= inv;
        int row = qbase + q;
        float* dst = (dg < D_HALF)
            ? out + (size_t)row * D_HALF + dg
            : out + (size_t)N_TOK * D_HALF + (size_t)row * D_HALF + (dg - D_HALF);
        *reinterpret_cast<f32x4*>(dst) = o;
    }
}

extern "C" void kernel_launch(void* const* d_in, const int* in_sizes, int n_in,
                              void* d_out, int out_size, void* d_ws, size_t ws_size,
                              hipStream_t stream)
{
    const float* mag   = (const float*)d_in[0];
    const float* phase = (const float*)d_in[1];
    float* out = (float*)d_out;

    __hip_bfloat16* Q  = (__hip_bfloat16*)d_ws;                  // 2 MB
    __hip_bfloat16* Vt = Q + (size_t)N_TOK * D_FULL;             // 2 MB

    precompute_kernel<<<(N_TOK * D_HALF + 255) / 256, 256, 0, stream>>>(mag, phase, Q, Vt);
    attn_kernel<<<N_TOK / QW, 768, 0, stream>>>(Q, Vt, out);
}

// Round 7
// 88.940 us; speedup vs baseline: 2.3465x; 1.5602x over previous
//
#include <hip/hip_runtime.h>
#include <hip/hip_bf16.h>

typedef __attribute__((ext_vector_type(8))) short short8;
typedef __attribute__((ext_vector_type(4))) float f32x4;
typedef __attribute__((ext_vector_type(16))) float f32x16;
typedef __attribute__((ext_vector_type(2))) int int2v;

#define N_TOK 8192
#define D_HALF 64
#define D_FULL 128
#define QW 32                     // q rows per block (one 32-col MFMA tile)
#define KT 64                     // keys per inner iteration
#define TILES_TOT (N_TOK / KT)    // 128
#define OSTR 132                  // padded LDS row stride (floats)
#define THR 8.0f

// Fragment-major layouts (short8 = 16B units):
//   Kf8[(panel*16 + ks*2 + hi)*32 + li]  = K[panel*32+li][ks*16+8*hi .. +8]
//   Vf8[(kc*4 + dblk)*64 + hi*32 + li]   = V^T[dblk*32+li][kc*16+8*hi .. +8]
// -> every fragment load is lane-contiguous (1KB per wave-instruction).
__global__ __launch_bounds__(256) void precompute_kernel(
    const float* __restrict__ mag, const float* __restrict__ phase,
    __hip_bfloat16* __restrict__ Kf, __hip_bfloat16* __restrict__ Vf)
{
    int idx = blockIdx.x * 256 + threadIdx.x;
    if (idx >= N_TOK * D_HALF) return;
    int n = idx >> 6, d0 = idx & 63;
    float m = mag[idx], p = phase[idx];
    float s, c;
    sincosf(p, &s, &c);

    // K (=Q) writes: value a at col d0, value b at col d0+64
    {
        float val[2] = { m * c, m * s };
        #pragma unroll
        for (int h = 0; h < 2; ++h) {
            int dc = d0 + 64 * h;
            int off = ((n >> 5) * 16 + (dc >> 4) * 2 + ((dc >> 3) & 1)) * 256
                      + (n & 31) * 8 + (dc & 7);
            Kf[off] = __float2bfloat16(val[h]);
        }
    }
    // V writes: mag at row-col (n, d0), phase at (n, d0+64)
    {
        float val[2] = { m, p };
        #pragma unroll
        for (int h = 0; h < 2; ++h) {
            int dv = d0 + 64 * h;
            int off = ((n >> 4) * 4 + (dv >> 5)) * 512 + ((n >> 3) & 1) * 256
                      + (dv & 31) * 8 + (n & 7);
            Vf[off] = __float2bfloat16(val[h]);
        }
    }
}

static __device__ __forceinline__ unsigned bfpair(float lo, float hi)
{
    __hip_bfloat16 l = __float2bfloat16(lo), h = __float2bfloat16(hi);
    unsigned short ul = *reinterpret_cast<unsigned short*>(&l);
    unsigned short uh = *reinterpret_cast<unsigned short*>(&h);
    return (unsigned)ul | ((unsigned)uh << 16);
}

// 768 threads = 12 waves, 1 block/CU -> 3 waves/SIMD (round-5 showed 4/SIMD
// spills the ~164-reg wave state). All waves share the block's 32 q rows;
// keys split 12-ways (uneven tiles). All global loads lane-contiguous.
__global__ __launch_bounds__(768, 3) void attn_kernel(
    const short8* __restrict__ Kf8, const short8* __restrict__ Vf8,
    float* __restrict__ out)
{
    __shared__ __align__(16) float O_lds[6][QW][OSTR];   // 101376 B (merge slots)
    __shared__ float ms_lds[6][2][QW];                   // 1536 B

    const int tid  = threadIdx.x;
    const int wid  = tid >> 6;    // 0..11
    const int lane = tid & 63;
    const int li   = lane & 31;   // q column (QK^T) / d row (PV)
    const int hi   = lane >> 5;

    const int qbase = blockIdx.x * QW;
    // uneven split of 128 tiles over 12 waves: waves 0-7 get 11, 8-11 get 10
    const int t_start = (wid < 8) ? 11 * wid : 88 + 10 * (wid - 8);
    const int t_count = (wid < 8) ? 11 : 10;

    // Q as B-operand: col = li (q row), k = d = ks*16 + 8*hi + i
    short8 bq[8];
    {
        const short8* qp = Kf8 + ((size_t)blockIdx.x * 16 + hi * 1) * 0 // (placate formatting)
                         + ((size_t)blockIdx.x * 16) * 32;
        #pragma unroll
        for (int ks = 0; ks < 8; ++ks)
            bq[ks] = qp[(ks * 2 + hi) * 32 + li];
    }

    f32x16 acc[4];   // O^T: acc[dblk], col = q = li, row = d-offset
    #pragma unroll
    for (int d = 0; d < 4; ++d) acc[d] = (f32x16)(0.0f);
    float mrow = -3.0e38f, srow = 0.0f;

    for (int t = 0; t < t_count; ++t) {
        const int kt = (t_start + t) * KT;

        // ---- S^T = K . Q : two 32x32 key-subtiles ----
        f32x16 st[2];
        __builtin_amdgcn_s_setprio(1);
        #pragma unroll
        for (int ksub = 0; ksub < 2; ++ksub) {
            st[ksub] = (f32x16)(0.0f);
            const short8* kp = Kf8 + (size_t)((kt >> 5) + ksub) * 512;  // panel*16*32
            #pragma unroll
            for (int ks = 0; ks < 8; ++ks) {
                short8 kf = kp[(ks * 2 + hi) * 32 + li];
                st[ksub] = __builtin_amdgcn_mfma_f32_32x32x16_bf16(kf, bq[ks], st[ksub], 0, 0, 0);
            }
        }
        __builtin_amdgcn_s_setprio(0);

        // ---- online softmax, lane-local (q = li; 32 of 64 keys here, rest on lane^32)
        float mx[16];
        #pragma unroll
        for (int r = 0; r < 16; ++r) mx[r] = fmaxf(st[0][r], st[1][r]);
        #pragma unroll
        for (int w = 8; w >= 1; w >>= 1)
            #pragma unroll
            for (int r = 0; r < w; ++r) mx[r] = fmaxf(mx[r], mx[r + w]);
        float pmax = fmaxf(mx[0], __shfl_xor(mx[0], 32));

        if (!__all(pmax - mrow <= THR)) {          // defer-max: rarely taken
            float mn  = fmaxf(mrow, pmax);
            float scl = __expf(mrow - mn);
            srow *= scl;
            #pragma unroll
            for (int d = 0; d < 4; ++d)
                #pragma unroll
                for (int r = 0; r < 16; ++r) acc[d][r] *= scl;
            mrow = mn;
        }

        #pragma unroll
        for (int ksub = 0; ksub < 2; ++ksub)
            #pragma unroll
            for (int r = 0; r < 16; ++r)
                st[ksub][r] = __expf(st[ksub][r] - mrow);

        float sm[16];
        #pragma unroll
        for (int r = 0; r < 16; ++r) sm[r] = st[0][r] + st[1][r];
        #pragma unroll
        for (int w = 8; w >= 1; w >>= 1)
            #pragma unroll
            for (int r = 0; r < w; ++r) sm[r] += sm[r + w];
        srow += sm[0] + __shfl_xor(sm[0], 32);

        // ---- PV: O^T += V^T . P, P repacked in-register via permlane32_swap ----
        // u.w[0]={a0.lo,b0.lo}, u.w[2]={a0.hi,b0.hi} -> swap(dst=a0, src=b0); ditto (a1,b1)
        #pragma unroll
        for (int c = 0; c < 4; ++c) {
            const f32x16& P = st[c >> 1];
            const int b = 8 * (c & 1);
            unsigned a0 = bfpair(P[b + 0], P[b + 1]);
            unsigned a1 = bfpair(P[b + 2], P[b + 3]);
            unsigned b0 = bfpair(P[b + 4], P[b + 5]);
            unsigned b1 = bfpair(P[b + 6], P[b + 7]);
            int2v r0 = __builtin_amdgcn_permlane32_swap((int)a0, (int)b0, false, false);
            int2v r1 = __builtin_amdgcn_permlane32_swap((int)a1, (int)b1, false, false);
            union { int w[4]; short8 v; } u;
            u.w[0] = r0[0]; u.w[1] = r1[0]; u.w[2] = r0[1]; u.w[3] = r1[1];

            const short8* vp = Vf8 + (size_t)((kt >> 4) + c) * 256 + hi * 32 + li;
            __builtin_amdgcn_s_setprio(1);
            #pragma unroll
            for (int d = 0; d < 4; ++d) {
                short8 vf = vp[d * 64];
                acc[d] = __builtin_amdgcn_mfma_f32_32x32x16_bf16(vf, u.v, acc[d], 0, 0, 0);
            }
            __builtin_amdgcn_s_setprio(0);
        }
    }

    // ---- k-split merge: 12 partials -> 6 -> 3 -> parallel 3-way final ----
    auto store_partial = [&](int slot) {
        #pragma unroll
        for (int d = 0; d < 4; ++d)
            #pragma unroll
            for (int rr = 0; rr < 4; ++rr) {
                f32x4 v;
                #pragma unroll
                for (int j = 0; j < 4; ++j) v[j] = acc[d][4 * rr + j];
                *reinterpret_cast<f32x4*>(&O_lds[slot][li][d * 32 + 8 * rr + 4 * hi]) = v;
            }
        if (hi == 0) { ms_lds[slot][0][li] = mrow; ms_lds[slot][1][li] = srow; }
    };
    auto merge_partial = [&](int slot) {
        float mb = ms_lds[slot][0][li], sb = ms_lds[slot][1][li];
        float M  = fmaxf(mrow, mb);
        float ea = __expf(mrow - M), eb = __expf(mb - M);
        srow = srow * ea + sb * eb;
        mrow = M;
        #pragma unroll
        for (int d = 0; d < 4; ++d)
            #pragma unroll
            for (int rr = 0; rr < 4; ++rr) {
                f32x4 v = *reinterpret_cast<const f32x4*>(&O_lds[slot][li][d * 32 + 8 * rr + 4 * hi]);
                #pragma unroll
                for (int j = 0; j < 4; ++j)
                    acc[d][4 * rr + j] = acc[d][4 * rr + j] * ea + v[j] * eb;
            }
    };

    __syncthreads();
    if (wid >= 6) store_partial(wid - 6);      // waves 6-11 -> slots 0-5
    __syncthreads();
    if (wid < 6) merge_partial(wid);           // waves 0-5 absorb
    __syncthreads();
    if (wid >= 3 && wid < 6) store_partial(wid - 3);  // waves 3-5 -> slots 0-2
    __syncthreads();
    if (wid < 3) merge_partial(wid);           // waves 0-2 absorb
    __syncthreads();
    if (wid < 3) store_partial(wid);           // final 3 partials -> slots 0-2
    __syncthreads();

    // ---- final 3-way merge + write; f32x4 chunks strided over 768 threads ----
    for (int i = tid; i < QW * D_FULL / 4; i += 768) {
        int q  = i >> 5;                 // 0..31
        int dg = (i & 31) * 4;           // 0..124
        float M = fmaxf(fmaxf(ms_lds[0][0][q], ms_lds[1][0][q]), ms_lds[2][0][q]);
        float e[3], S = 0.0f;
        #pragma unroll
        for (int s = 0; s < 3; ++s) {
            e[s] = __expf(ms_lds[s][0][q] - M);
            S += ms_lds[s][1][q] * e[s];
        }
        float inv = 1.0f / S;
        f32x4 o = (f32x4)(0.0f);
        #pragma unroll
        for (int s = 0; s < 3; ++s) {
            f32x4 u = *reinterpret_cast<const f32x4*>(&O_lds[s][q][dg]);
            #pragma unroll
            for (int j = 0; j < 4; ++j) o[j] += u[j] * e[s];
        }
        #pragma unroll
        for (int j = 0; j < 4; ++j) o[j] *= inv;
        int row = qbase + q;
        float* dst = (dg < D_HALF)
            ? out + (size_t)row * D_HALF + dg
            : out + (size_t)N_TOK * D_HALF + (size_t)row * D_HALF + (dg - D_HALF);
        *reinterpret_cast<f32x4*>(dst) = o;
    }
}

extern "C" void kernel_launch(void* const* d_in, const int* in_sizes, int n_in,
                              void* d_out, int out_size, void* d_ws, size_t ws_size,
                              hipStream_t stream)
{
    const float* mag   = (const float*)d_in[0];
    const float* phase = (const float*)d_in[1];
    float* out = (float*)d_out;

    __hip_bfloat16* Kf = (__hip_bfloat16*)d_ws;                  // 2 MB
    __hip_bfloat16* Vf = Kf + (size_t)N_TOK * D_FULL;            // 2 MB

    precompute_kernel<<<(N_TOK * D_HALF + 255) / 256, 256, 0, stream>>>(mag, phase, Kf, Vf);
    attn_kernel<<<N_TOK / QW, 768, 0, stream>>>((const short8*)Kf, (const short8*)Vf, out);
}

// Round 9
// 83.599 us; speedup vs baseline: 2.4964x; 1.0639x over previous
//
#include <hip/hip_runtime.h>
#include <hip/hip_bf16.h>

typedef __attribute__((ext_vector_type(8))) short short8;
typedef __attribute__((ext_vector_type(4))) float f32x4;
typedef __attribute__((ext_vector_type(16))) float f32x16;
typedef __attribute__((ext_vector_type(2))) int int2v;

#define N_TOK 8192
#define D_HALF 64
#define D_FULL 128
#define QW 32                      // q rows per block
#define CHUNK 256                  // keys staged per chunk (64KB K + 64KB V)
#define NCHUNK (N_TOK / CHUNK)     // 32
#define OSTR 132                   // padded merge-LDS row stride (floats)
#define THR 8.0f

// Fragment-major layouts (short8 = 16B units):
//   Kf8[(panel*16 + ks*2 + hi)*32 + li]  = K[panel*32+li][ks*16+8*hi .. +8]
//   Vf8[(kc*4 + dblk)*64 + hi*32 + li]   = V^T[dblk*32+li][kc*16+8*hi .. +8]
// -> every fragment load/stage is lane-contiguous; a 256-key chunk of K or V
//    is one contiguous 64KB span (pure linear global_load_lds staging).
__global__ __launch_bounds__(256) void precompute_kernel(
    const float* __restrict__ mag, const float* __restrict__ phase,
    __hip_bfloat16* __restrict__ Kf, __hip_bfloat16* __restrict__ Vf)
{
    int idx = blockIdx.x * 256 + threadIdx.x;
    if (idx >= N_TOK * D_HALF) return;
    int n = idx >> 6, d0 = idx & 63;
    float m = mag[idx], p = phase[idx];
    float s, c;
    sincosf(p, &s, &c);

    {
        float val[2] = { m * c, m * s };
        #pragma unroll
        for (int h = 0; h < 2; ++h) {
            int dc = d0 + 64 * h;
            int off = ((n >> 5) * 16 + (dc >> 4) * 2 + ((dc >> 3) & 1)) * 256
                      + (n & 31) * 8 + (dc & 7);
            Kf[off] = __float2bfloat16(val[h]);
        }
    }
    {
        float val[2] = { m, p };
        #pragma unroll
        for (int h = 0; h < 2; ++h) {
            int dv = d0 + 64 * h;
            int off = ((n >> 4) * 4 + (dv >> 5)) * 512 + ((n >> 3) & 1) * 256
                      + (dv & 31) * 8 + (n & 7);
            Vf[off] = __float2bfloat16(val[h]);
        }
    }
}

static __device__ __forceinline__ unsigned bfpair(float lo, float hi)
{
    __hip_bfloat16 l = __float2bfloat16(lo), h = __float2bfloat16(hi);
    unsigned short ul = *reinterpret_cast<unsigned short*>(&l);
    unsigned short uh = *reinterpret_cast<unsigned short*>(&h);
    return (unsigned)ul | ((unsigned)uh << 16);
}

// 512 threads = 8 waves, 1 block/CU. DMA ping-pong: stage 256-key chunks of
// K/V into LDS via global_load_lds; each wave computes one 32x32 S-tile per
// chunk (keys = wave's panel). Latency hiding comes from the DMA in flight
// across the opposite compute phase, not from wave count (R7: MLP~1/wave was
// the wall; R6: extra waves bought nothing).
__global__ __launch_bounds__(512, 2) void attn_kernel(
    const short8* __restrict__ Kf8, const short8* __restrict__ Vf8,
    float* __restrict__ out)
{
    __shared__ __align__(16) char smem[131072];   // Kbuf 64KB | Vbuf 64KB
    __shared__ float ms_lds[4][2][QW];

    short8* ldsK = (short8*)smem;
    short8* ldsV = (short8*)(smem + 65536);
    float (*O_lds)[QW][OSTR] = (float (*)[QW][OSTR])smem;  // merge reuse

    const int tid  = threadIdx.x;
    const int wid  = tid >> 6;    // 0..7
    const int lane = tid & 63;
    const int li   = lane & 31;   // q column (QK^T) / d row (PV)
    const int hi   = lane >> 5;

    const int qbase = blockIdx.x * QW;

    // stage one contiguous 64KB chunk: 512 thr x 16B x 8 issues
    auto stage = [&](const short8* gsrc, char* lbase) {
        const char* g = (const char*)gsrc;
        #pragma unroll
        for (int j = 0; j < 8; ++j)
            __builtin_amdgcn_global_load_lds(
                (const __attribute__((address_space(1))) void*)(g + j * 8192 + tid * 16),
                (__attribute__((address_space(3))) void*)(lbase + j * 8192 + wid * 1024),
                16, 0, 0);
    };

    // Q as B-operand: col = li (q row), k = d = ks*16 + 8*hi + i
    short8 bq[8];
    {
        const short8* qp = Kf8 + (size_t)blockIdx.x * 512;
        #pragma unroll
        for (int ks = 0; ks < 8; ++ks)
            bq[ks] = qp[(ks * 2 + hi) * 32 + li];
    }

    f32x16 acc[4];   // O^T: acc[dblk], col = q = li
    #pragma unroll
    for (int d = 0; d < 4; ++d) acc[d] = (f32x16)(0.0f);
    float mrow = -3.0e38f, srow = 0.0f;

    stage(Kf8, smem);                              // K(0)
    stage(Vf8, smem + 65536);                      // V(0)
    __syncthreads();                               // prologue drain (both)

    for (int t = 0; t < NCHUNK; ++t) {
        // ---- Phase A: S^T = K.Q from Kbuf (V(t) DMA in flight for t>0) ----
        f32x16 st = (f32x16)(0.0f);
        __builtin_amdgcn_s_setprio(1);
        #pragma unroll
        for (int ks = 0; ks < 8; ++ks) {
            short8 kf = ldsK[wid * 512 + (ks * 2 + hi) * 32 + li];
            st = __builtin_amdgcn_mfma_f32_32x32x16_bf16(kf, bq[ks], st, 0, 0, 0);
        }
        __builtin_amdgcn_s_setprio(0);

        // online softmax, lane-local (q=li; this wave's 32 keys split 16/16
        // with lane^32 per the 32x32 C-layout)
        float mx[8];
        #pragma unroll
        for (int r = 0; r < 8; ++r) mx[r] = fmaxf(st[r], st[r + 8]);
        #pragma unroll
        for (int w = 4; w >= 1; w >>= 1)
            #pragma unroll
            for (int r = 0; r < w; ++r) mx[r] = fmaxf(mx[r], mx[r + w]);
        float pmax = fmaxf(mx[0], __shfl_xor(mx[0], 32));

        if (!__all(pmax - mrow <= THR)) {          // defer-max: rarely taken
            float mn  = fmaxf(mrow, pmax);
            float scl = __expf(mrow - mn);
            srow *= scl;
            #pragma unroll
            for (int d = 0; d < 4; ++d)
                #pragma unroll
                for (int r = 0; r < 16; ++r) acc[d][r] *= scl;
            mrow = mn;
        }

        #pragma unroll
        for (int r = 0; r < 16; ++r) st[r] = __expf(st[r] - mrow);
        float sm[8];
        #pragma unroll
        for (int r = 0; r < 8; ++r) sm[r] = st[r] + st[r + 8];
        #pragma unroll
        for (int w = 4; w >= 1; w >>= 1)
            #pragma unroll
            for (int r = 0; r < w; ++r) sm[r] += sm[r + w];
        srow += sm[0] + __shfl_xor(sm[0], 32);

        __syncthreads();                           // drains V(t); Kbuf readers done
        if (t + 1 < NCHUNK)
            stage(Kf8 + (size_t)(t + 1) * 4096, smem);        // K(t+1) -> Kbuf

        // ---- Phase B: O^T += V^T.P from Vbuf (K(t+1) DMA in flight) ----
        // P repack via permlane32_swap: u.w[0]={a0.lo,b0.lo}, u.w[2]={a0.hi,b0.hi}
        #pragma unroll
        for (int c = 0; c < 2; ++c) {
            const int b = 8 * c;
            unsigned a0 = bfpair(st[b + 0], st[b + 1]);
            unsigned a1 = bfpair(st[b + 2], st[b + 3]);
            unsigned b0 = bfpair(st[b + 4], st[b + 5]);
            unsigned b1 = bfpair(st[b + 6], st[b + 7]);
            int2v r0 = __builtin_amdgcn_permlane32_swap((int)a0, (int)b0, false, false);
            int2v r1 = __builtin_amdgcn_permlane32_swap((int)a1, (int)b1, false, false);
            union { int w[4]; short8 v; } u;
            u.w[0] = r0[0]; u.w[1] = r1[0]; u.w[2] = r0[1]; u.w[3] = r1[1];

            const short8* vp = ldsV + (wid * 2 + c) * 256 + hi * 32 + li;
            __builtin_amdgcn_s_setprio(1);
            #pragma unroll
            for (int d = 0; d < 4; ++d) {
                short8 vf = vp[d * 64];
                acc[d] = __builtin_amdgcn_mfma_f32_32x32x16_bf16(vf, u.v, acc[d], 0, 0, 0);
            }
            __builtin_amdgcn_s_setprio(0);
        }

        __syncthreads();                           // drains K(t+1); Vbuf readers done
        if (t + 1 < NCHUNK)
            stage(Vf8 + (size_t)(t + 1) * 4096, smem + 65536); // V(t+1) -> Vbuf
    }

    // ---- k-split merge: 8 partials -> 4 -> parallel 4-way final ----
    auto store_partial = [&](int slot) {
        #pragma unroll
        for (int d = 0; d < 4; ++d)
            #pragma unroll
            for (int rr = 0; rr < 4; ++rr) {
                f32x4 v;
                #pragma unroll
                for (int j = 0; j < 4; ++j) v[j] = acc[d][4 * rr + j];
                *reinterpret_cast<f32x4*>(&O_lds[slot][li][d * 32 + 8 * rr + 4 * hi]) = v;
            }
        if (hi == 0) { ms_lds[slot][0][li] = mrow; ms_lds[slot][1][li] = srow; }
    };
    auto merge_partial = [&](int slot) {
        float mb = ms_lds[slot][0][li], sb = ms_lds[slot][1][li];
        float M  = fmaxf(mrow, mb);
        float ea = __expf(mrow - M), eb = __expf(mb - M);
        srow = srow * ea + sb * eb;
        mrow = M;
        #pragma unroll
        for (int d = 0; d < 4; ++d)
            #pragma unroll
            for (int rr = 0; rr < 4; ++rr) {
                f32x4 v = *reinterpret_cast<const f32x4*>(&O_lds[slot][li][d * 32 + 8 * rr + 4 * hi]);
                #pragma unroll
                for (int j = 0; j < 4; ++j)
                    acc[d][4 * rr + j] = acc[d][4 * rr + j] * ea + v[j] * eb;
            }
    };

    __syncthreads();                       // staging dead; safe to reuse as O_lds
    if (wid >= 4) store_partial(wid - 4);  // waves 4-7 -> slots 0-3
    __syncthreads();
    if (wid < 4) merge_partial(wid);       // waves 0-3 absorb
    __syncthreads();
    if (wid < 4) store_partial(wid);       // final 4 partials -> slots 0-3
    __syncthreads();

    // ---- final 4-way merge + write; thread -> (q, 8 d's) ----
    {
        int q  = tid >> 4;                 // 0..31
        int dg = (tid & 15) * 8;           // 0..120
        float M = ms_lds[0][0][q];
        #pragma unroll
        for (int s = 1; s < 4; ++s) M = fmaxf(M, ms_lds[s][0][q]);
        float e[4], S = 0.0f;
        #pragma unroll
        for (int s = 0; s < 4; ++s) {
            e[s] = __expf(ms_lds[s][0][q] - M);
            S += ms_lds[s][1][q] * e[s];
        }
        float inv = 1.0f / S;
        f32x4 o0 = (f32x4)(0.0f), o1 = (f32x4)(0.0f);
        #pragma unroll
        for (int s = 0; s < 4; ++s) {
            f32x4 u0 = *reinterpret_cast<const f32x4*>(&O_lds[s][q][dg]);
            f32x4 u1 = *reinterpret_cast<const f32x4*>(&O_lds[s][q][dg + 4]);
            #pragma unroll
            for (int j = 0; j < 4; ++j) { o0[j] += u0[j] * e[s]; o1[j] += u1[j] * e[s]; }
        }
        #pragma unroll
        for (int j = 0; j < 4; ++j) { o0[j] *= inv; o1[j] *= inv; }
        int row = qbase + q;
        float* dst = (dg < D_HALF)
            ? out + (size_t)row * D_HALF + dg
            : out + (size_t)N_TOK * D_HALF + (size_t)row * D_HALF + (dg - D_HALF);
        *reinterpret_cast<f32x4*>(dst)     = o0;
        *reinterpret_cast<f32x4*>(dst + 4) = o1;
    }
}

extern "C" void kernel_launch(void* const* d_in, const int* in_sizes, int n_in,
                              void* d_out, int out_size, void* d_ws, size_t ws_size,
                              hipStream_t stream)
{
    const float* mag   = (const float*)d_in[0];
    const float* phase = (const float*)d_in[1];
    float* out = (float*)d_out;

    __hip_bfloat16* Kf = (__hip_bfloat16*)d_ws;                  // 2 MB
    __hip_bfloat16* Vf = Kf + (size_t)N_TOK * D_FULL;            // 2 MB

    precompute_kernel<<<(N_TOK * D_HALF + 255) / 256, 256, 0, stream>>>(mag, phase, Kf, Vf);
    attn_kernel<<<N_TOK / QW, 512, 0, stream>>>((const short8*)Kf, (const short8*)Vf, out);
}

// Round 10
// 66.311 us; speedup vs baseline: 3.1472x; 1.2607x over previous
//
#include <hip/hip_runtime.h>
#include <hip/hip_bf16.h>

typedef __attribute__((ext_vector_type(8))) short short8;
typedef __attribute__((ext_vector_type(4))) float f32x4;
typedef __attribute__((ext_vector_type(16))) float f32x16;
typedef __attribute__((ext_vector_type(2))) int int2v;

#define N_TOK 8192
#define D_HALF 64
#define D_FULL 128
#define QB 64                      // q rows per block
#define KHALF 4096                 // keys per block (k-split 2)
#define CHUNK 128                  // keys staged per chunk (32KB K + 32KB V)
#define NCH (KHALF / CHUNK)        // 32
#define OSTR 132
#define THR 8.0f

// Fragment-major layouts (short8 = 16B units):
//   Kf8[(panel*16 + ks*2 + hi)*32 + li]  = K[panel*32+li][ks*16+8*hi .. +8]
//   Vf8[(kc*4 + dblk)*64 + hi*32 + li]   = V^T[dblk*32+li][kc*16+8*hi .. +8]
__global__ __launch_bounds__(256) void precompute_kernel(
    const float* __restrict__ mag, const float* __restrict__ phase,
    __hip_bfloat16* __restrict__ Kf, __hip_bfloat16* __restrict__ Vf)
{
    int idx = blockIdx.x * 256 + threadIdx.x;
    if (idx >= N_TOK * D_HALF) return;
    int n = idx >> 6, d0 = idx & 63;
    float m = mag[idx], p = phase[idx];
    float s, c;
    sincosf(p, &s, &c);
    {
        float val[2] = { m * c, m * s };
        #pragma unroll
        for (int h = 0; h < 2; ++h) {
            int dc = d0 + 64 * h;
            int off = ((n >> 5) * 16 + (dc >> 4) * 2 + ((dc >> 3) & 1)) * 256
                      + (n & 31) * 8 + (dc & 7);
            Kf[off] = __float2bfloat16(val[h]);
        }
    }
    {
        float val[2] = { m, p };
        #pragma unroll
        for (int h = 0; h < 2; ++h) {
            int dv = d0 + 64 * h;
            int off = ((n >> 4) * 4 + (dv >> 5)) * 512 + ((n >> 3) & 1) * 256
                      + (dv & 31) * 8 + (n & 7);
            Vf[off] = __float2bfloat16(val[h]);
        }
    }
}

static __device__ __forceinline__ unsigned bfpair(float lo, float hi)
{
    __hip_bfloat16 l = __float2bfloat16(lo), h = __float2bfloat16(hi);
    unsigned short ul = *reinterpret_cast<unsigned short*>(&l);
    unsigned short uh = *reinterpret_cast<unsigned short*>(&h);
    return (unsigned)ul | ((unsigned)uh << 16);
}

// 512 thr = 8 waves = (qh 0/1) x (kp 0..3). Block owns 64 q-rows and HALF the
// keys (k-split 2 across blocks): per-block KV stream 2MB (was 4MB) -> halves
// the per-CU L2 delivery that R9 showed is the wall (~21-25 B/cy/CU).
// Per-wave body identical to R9. Partials (O,m,s) -> ws, merged by merge2.
__global__ __launch_bounds__(512, 2) void attn_kernel(
    const short8* __restrict__ Kf8, const short8* __restrict__ Vf8,
    float* __restrict__ Opart, float* __restrict__ Mp, float* __restrict__ Sp)
{
    __shared__ __align__(16) char smem[68608];   // staging 64KB | merge 67.5KB (reused)
    short8* ldsK = (short8*)smem;                        // 32KB
    short8* ldsV = (short8*)(smem + 32768);              // 32KB
    float (*O_lds)[32][OSTR] = (float (*)[32][OSTR])smem; // 4 slots, 67584B
    float* ms_base = (float*)(smem + 67584);             // [4][2][32] = 1KB

    const int tid  = threadIdx.x;
    const int wid  = tid >> 6;     // 0..7
    const int lane = tid & 63;
    const int li   = lane & 31;
    const int hi   = lane >> 5;
    const int qh   = wid >> 2;     // q sub-tile 0/1
    const int kp   = wid & 3;      // key panel within chunk

    const int bid  = blockIdx.x;
    const int qt   = bid >> 1;     // 0..127
    const int kh   = bid & 1;      // key half
    const int rot  = bid & 31;

    auto msm = [&](int slot, int which) -> float* { return ms_base + (slot * 2 + which) * 32; };

    // stage one contiguous 32KB chunk: 512 thr x 16B x 4 issues
    auto stage = [&](const short8* gsrc, char* lbase) {
        const char* g = (const char*)gsrc;
        #pragma unroll
        for (int j = 0; j < 4; ++j)
            __builtin_amdgcn_global_load_lds(
                (const __attribute__((address_space(1))) void*)(g + j * 8192 + tid * 16),
                (__attribute__((address_space(3))) void*)(lbase + j * 8192 + wid * 1024),
                16, 0, 0);
    };

    // Q as B-operand for this wave's 32 q-rows (panel qt*2+qh)
    short8 bq[8];
    {
        const short8* qp = Kf8 + (size_t)(qt * 2 + qh) * 512;
        #pragma unroll
        for (int ks = 0; ks < 8; ++ks)
            bq[ks] = qp[(ks * 2 + hi) * 32 + li];
    }

    f32x16 acc[4];
    #pragma unroll
    for (int d = 0; d < 4; ++d) acc[d] = (f32x16)(0.0f);
    float mrow = -3.0e38f, srow = 0.0f;

    {
        int ck0 = kh * NCH + rot;
        stage(Kf8 + (size_t)ck0 * 2048, smem);
        stage(Vf8 + (size_t)ck0 * 2048, smem + 32768);
    }
    __syncthreads();

    for (int t = 0; t < NCH; ++t) {
        // ---- Phase A: S^T = K.Q from Kbuf (V(t) DMA in flight for t>0) ----
        f32x16 st = (f32x16)(0.0f);
        __builtin_amdgcn_s_setprio(1);
        #pragma unroll
        for (int ks = 0; ks < 8; ++ks) {
            short8 kf = ldsK[kp * 512 + (ks * 2 + hi) * 32 + li];
            st = __builtin_amdgcn_mfma_f32_32x32x16_bf16(kf, bq[ks], st, 0, 0, 0);
        }
        __builtin_amdgcn_s_setprio(0);

        // online softmax (lane-local; 16/16 key split with lane^32)
        float mx[8];
        #pragma unroll
        for (int r = 0; r < 8; ++r) mx[r] = fmaxf(st[r], st[r + 8]);
        #pragma unroll
        for (int w = 4; w >= 1; w >>= 1)
            #pragma unroll
            for (int r = 0; r < w; ++r) mx[r] = fmaxf(mx[r], mx[r + w]);
        float pmax = fmaxf(mx[0], __shfl_xor(mx[0], 32));

        if (!__all(pmax - mrow <= THR)) {
            float mn  = fmaxf(mrow, pmax);
            float scl = __expf(mrow - mn);
            srow *= scl;
            #pragma unroll
            for (int d = 0; d < 4; ++d)
                #pragma unroll
                for (int r = 0; r < 16; ++r) acc[d][r] *= scl;
            mrow = mn;
        }

        #pragma unroll
        for (int r = 0; r < 16; ++r) st[r] = __expf(st[r] - mrow);
        float sm[8];
        #pragma unroll
        for (int r = 0; r < 8; ++r) sm[r] = st[r] + st[r + 8];
        #pragma unroll
        for (int w = 4; w >= 1; w >>= 1)
            #pragma unroll
            for (int r = 0; r < w; ++r) sm[r] += sm[r + w];
        srow += sm[0] + __shfl_xor(sm[0], 32);

        __syncthreads();                       // drains V(t); Kbuf readers done
        if (t + 1 < NCH) {
            int ck = kh * NCH + ((t + 1 + rot) & (NCH - 1));
            stage(Kf8 + (size_t)ck * 2048, smem);
        }

        // ---- Phase B: O^T += V^T.P (K(t+1) DMA in flight) ----
        #pragma unroll
        for (int c = 0; c < 2; ++c) {
            const int b = 8 * c;
            unsigned a0 = bfpair(st[b + 0], st[b + 1]);
            unsigned a1 = bfpair(st[b + 2], st[b + 3]);
            unsigned b0 = bfpair(st[b + 4], st[b + 5]);
            unsigned b1 = bfpair(st[b + 6], st[b + 7]);
            int2v r0 = __builtin_amdgcn_permlane32_swap((int)a0, (int)b0, false, false);
            int2v r1 = __builtin_amdgcn_permlane32_swap((int)a1, (int)b1, false, false);
            union { int w[4]; short8 v; } u;
            u.w[0] = r0[0]; u.w[1] = r1[0]; u.w[2] = r0[1]; u.w[3] = r1[1];

            const short8* vp = ldsV + (kp * 2 + c) * 256 + hi * 32 + li;
            __builtin_amdgcn_s_setprio(1);
            #pragma unroll
            for (int d = 0; d < 4; ++d) {
                short8 vf = vp[d * 64];
                acc[d] = __builtin_amdgcn_mfma_f32_32x32x16_bf16(vf, u.v, acc[d], 0, 0, 0);
            }
            __builtin_amdgcn_s_setprio(0);
        }

        __syncthreads();                       // drains K(t+1); Vbuf readers done
        if (t + 1 < NCH) {
            int ck = kh * NCH + ((t + 1 + rot) & (NCH - 1));
            stage(Vf8 + (size_t)ck * 2048, smem + 32768);
        }
    }

    // ---- in-block merge over kp (per qh group): 4 -> 2 -> final 2-way ----
    auto store_partial = [&](int slot) {
        #pragma unroll
        for (int d = 0; d < 4; ++d)
            #pragma unroll
            for (int rr = 0; rr < 4; ++rr) {
                f32x4 v;
                #pragma unroll
                for (int j = 0; j < 4; ++j) v[j] = acc[d][4 * rr + j];
                *reinterpret_cast<f32x4*>(&O_lds[slot][li][d * 32 + 8 * rr + 4 * hi]) = v;
            }
        if (hi == 0) { msm(slot, 0)[li] = mrow; msm(slot, 1)[li] = srow; }
    };
    auto merge_partial = [&](int slot) {
        float mb = msm(slot, 0)[li], sb = msm(slot, 1)[li];
        float M  = fmaxf(mrow, mb);
        float ea = __expf(mrow - M), eb = __expf(mb - M);
        srow = srow * ea + sb * eb;
        mrow = M;
        #pragma unroll
        for (int d = 0; d < 4; ++d)
            #pragma unroll
            for (int rr = 0; rr < 4; ++rr) {
                f32x4 v = *reinterpret_cast<const f32x4*>(&O_lds[slot][li][d * 32 + 8 * rr + 4 * hi]);
                #pragma unroll
                for (int j = 0; j < 4; ++j)
                    acc[d][4 * rr + j] = acc[d][4 * rr + j] * ea + v[j] * eb;
            }
    };

    __syncthreads();                         // staging dead; reuse as merge space
    if (kp >= 2) store_partial(qh * 2 + (kp - 2));
    __syncthreads();
    if (kp < 2) merge_partial(qh * 2 + kp);
    __syncthreads();
    if (kp < 2) store_partial(qh * 2 + kp);
    __syncthreads();

    // ---- final 2-way merge per q-group; write UNNORMALIZED partial to ws ----
    #pragma unroll
    for (int u0 = 0; u0 < 2; ++u0) {
        int u  = tid + u0 * 512;           // 0..1023
        int q  = u >> 4;                   // 0..63
        int dg = (u & 15) * 8;             // 0..120
        int grp = q >> 5, qq = q & 31;
        float m0 = msm(grp * 2 + 0, 0)[qq], s0 = msm(grp * 2 + 0, 1)[qq];
        float m1 = msm(grp * 2 + 1, 0)[qq], s1 = msm(grp * 2 + 1, 1)[qq];
        float M  = fmaxf(m0, m1);
        float e0 = __expf(m0 - M), e1 = __expf(m1 - M);
        float S  = s0 * e0 + s1 * e1;
        f32x4 o0, o1;
        #pragma unroll
        for (int j = 0; j < 4; ++j) {
            o0[j] = O_lds[grp * 2 + 0][qq][dg + j]     * e0 + O_lds[grp * 2 + 1][qq][dg + j]     * e1;
            o1[j] = O_lds[grp * 2 + 0][qq][dg + 4 + j] * e0 + O_lds[grp * 2 + 1][qq][dg + 4 + j] * e1;
        }
        size_t pidx = (size_t)bid * QB + q;
        *reinterpret_cast<f32x4*>(&Opart[pidx * D_FULL + dg])     = o0;
        *reinterpret_cast<f32x4*>(&Opart[pidx * D_FULL + dg + 4]) = o1;
        if (dg == 0) { Mp[pidx] = M; Sp[pidx] = S; }
    }
}

// combine the two k-half partials per q-row and write final output
__global__ __launch_bounds__(256) void merge2_kernel(
    const float* __restrict__ Opart, const float* __restrict__ Mp,
    const float* __restrict__ Sp, float* __restrict__ out)
{
    int i   = blockIdx.x * 256 + threadIdx.x;   // 262144 total, 4 floats each
    int row = i >> 5;                           // 0..8191
    int dg  = (i & 31) * 4;                     // 0..124
    int qt  = row >> 6, qq = row & 63;
    size_t p0 = (size_t)(qt * 2 + 0) * QB + qq;
    size_t p1 = (size_t)(qt * 2 + 1) * QB + qq;
    float m0 = Mp[p0], m1 = Mp[p1], s0 = Sp[p0], s1 = Sp[p1];
    float M  = fmaxf(m0, m1);
    float e0 = __expf(m0 - M), e1 = __expf(m1 - M);
    float inv = 1.0f / (s0 * e0 + s1 * e1);
    f32x4 a = *reinterpret_cast<const f32x4*>(&Opart[p0 * D_FULL + dg]);
    f32x4 b = *reinterpret_cast<const f32x4*>(&Opart[p1 * D_FULL + dg]);
    f32x4 o;
    #pragma unroll
    for (int j = 0; j < 4; ++j) o[j] = (a[j] * e0 + b[j] * e1) * inv;
    float* dst = (dg < D_HALF)
        ? out + (size_t)row * D_HALF + dg
        : out + (size_t)N_TOK * D_HALF + (size_t)row * D_HALF + (dg - D_HALF);
    *reinterpret_cast<f32x4*>(dst) = o;
}

extern "C" void kernel_launch(void* const* d_in, const int* in_sizes, int n_in,
                              void* d_out, int out_size, void* d_ws, size_t ws_size,
                              hipStream_t stream)
{
    const float* mag   = (const float*)d_in[0];
    const float* phase = (const float*)d_in[1];
    float* out = (float*)d_out;

    char* ws = (char*)d_ws;
    __hip_bfloat16* Kf = (__hip_bfloat16*)ws;                    // 2 MB
    __hip_bfloat16* Vf = Kf + (size_t)N_TOK * D_FULL;            // 2 MB
    float* Opart = (float*)(ws + 4u * 1024 * 1024);              // 8 MB
    float* Mp    = (float*)(ws + 12u * 1024 * 1024);             // 64 KB
    float* Sp    = Mp + 16384;                                   // 64 KB

    precompute_kernel<<<(N_TOK * D_HALF + 255) / 256, 256, 0, stream>>>(mag, phase, Kf, Vf);
    attn_kernel<<<256, 512, 0, stream>>>((const short8*)Kf, (const short8*)Vf, Opart, Mp, Sp);
    merge2_kernel<<<1024, 256, 0, stream>>>(Opart, Mp, Sp, out);
}

// Round 11
// 64.915 us; speedup vs baseline: 3.2149x; 1.0215x over previous
//
#include <hip/hip_runtime.h>
#include <hip/hip_bf16.h>

typedef __attribute__((ext_vector_type(8))) short short8;
typedef __attribute__((ext_vector_type(4))) float f32x4;
typedef __attribute__((ext_vector_type(16))) float f32x16;
typedef __attribute__((ext_vector_type(2))) int int2v;

#define N_TOK 8192
#define D_HALF 64
#define D_FULL 128
#define QB 128                     // q rows per block (4 sub-tiles of 32)
#define KQ 2048                    // keys per block (k-split 4)
#define CHUNK 128                  // keys staged per chunk (32KB K + 32KB V)
#define NCH (KQ / CHUNK)           // 16
#define OSTR 132
#define THR 8.0f

// Fragment-major layouts (short8 = 16B units):
//   Kf8[(panel*16 + ks*2 + hi)*32 + li]  = K[panel*32+li][ks*16+8*hi .. +8]
//   Vf8[(kc*4 + dblk)*64 + hi*32 + li]   = V^T[dblk*32+li][kc*16+8*hi .. +8]
// A 128-key chunk of K or V is one contiguous 32KB span.
__global__ __launch_bounds__(256) void precompute_kernel(
    const float* __restrict__ mag, const float* __restrict__ phase,
    __hip_bfloat16* __restrict__ Kf, __hip_bfloat16* __restrict__ Vf)
{
    int idx = blockIdx.x * 256 + threadIdx.x;
    if (idx >= N_TOK * D_HALF) return;
    int n = idx >> 6, d0 = idx & 63;
    float m = mag[idx], p = phase[idx];
    float s, c;
    sincosf(p, &s, &c);
    {
        float val[2] = { m * c, m * s };
        #pragma unroll
        for (int h = 0; h < 2; ++h) {
            int dc = d0 + 64 * h;
            int off = ((n >> 5) * 16 + (dc >> 4) * 2 + ((dc >> 3) & 1)) * 256
                      + (n & 31) * 8 + (dc & 7);
            Kf[off] = __float2bfloat16(val[h]);
        }
    }
    {
        float val[2] = { m, p };
        #pragma unroll
        for (int h = 0; h < 2; ++h) {
            int dv = d0 + 64 * h;
            int off = ((n >> 4) * 4 + (dv >> 5)) * 512 + ((n >> 3) & 1) * 256
                      + (dv & 31) * 8 + (n & 7);
            Vf[off] = __float2bfloat16(val[h]);
        }
    }
}

static __device__ __forceinline__ unsigned bfpair(float lo, float hi)
{
    __hip_bfloat16 l = __float2bfloat16(lo), h = __float2bfloat16(hi);
    unsigned short ul = *reinterpret_cast<unsigned short*>(&l);
    unsigned short uh = *reinterpret_cast<unsigned short*>(&h);
    return (unsigned)ul | ((unsigned)uh << 16);
}

// 512 thr = 8 waves = (qh 0..3) x (kp 0..1); each wave handles panels
// {kp, kp+2} of each 128-key chunk. Counted-vmcnt deep pipeline (T4):
// raw s_barrier + s_waitcnt vmcnt(8) keeps 2 stages (128KB/CU) in flight --
// R10's __syncthreads ping-pong drained vmcnt(0) per phase and serialized
// on DMA latency (~14 B/cy/CU observed).
__global__ __launch_bounds__(512, 2) void attn_kernel(
    const short8* __restrict__ Kf8, const short8* __restrict__ Vf8,
    float* __restrict__ Opart, float* __restrict__ Mp, float* __restrict__ Sp)
{
    __shared__ __align__(16) char smem[131072];  // 2 x (K 32KB | V 32KB)

    const int tid  = threadIdx.x;
    const int wid  = tid >> 6;     // 0..7
    const int lane = tid & 63;
    const int li   = lane & 31;
    const int hi   = lane >> 5;
    const int qh   = wid >> 1;     // q sub-tile 0..3
    const int kp   = wid & 1;      // key panel group

    const int bid  = blockIdx.x;
    const int qt   = bid >> 2;     // 0..63
    const int kq   = bid & 3;      // key quarter
    const int rot  = bid & (NCH - 1);

    float (*O_lds)[32][OSTR] = (float (*)[32][OSTR])smem;   // merge reuse, 67584B
    float* ms_base = (float*)(smem + 67584);                // [4][2][32]
    auto msm = [&](int slot, int which) -> float* { return ms_base + (slot * 2 + which) * 32; };

    // stage K-chunk + V-chunk (32KB each) for physical chunk ck into buffer
    auto stageKV = [&](int ck, char* lbase) {
        const char* gk = (const char*)(Kf8 + (size_t)ck * 2048);
        const char* gv = (const char*)(Vf8 + (size_t)ck * 2048);
        #pragma unroll
        for (int j = 0; j < 4; ++j)
            __builtin_amdgcn_global_load_lds(
                (const __attribute__((address_space(1))) void*)(gk + j * 8192 + tid * 16),
                (__attribute__((address_space(3))) void*)(lbase + j * 8192 + tid * 16),
                16, 0, 0);
        #pragma unroll
        for (int j = 0; j < 4; ++j)
            __builtin_amdgcn_global_load_lds(
                (const __attribute__((address_space(1))) void*)(gv + j * 8192 + tid * 16),
                (__attribute__((address_space(3))) void*)(lbase + 32768 + j * 8192 + tid * 16),
                16, 0, 0);
    };
    auto ck_of = [&](int t) { return kq * NCH + ((t + rot) & (NCH - 1)); };

    // Q fragments FIRST (oldest in vmcnt queue, so counted waits stay exact)
    short8 bq[8];
    {
        const short8* qp = Kf8 + (size_t)(qt * 4 + qh) * 512;
        #pragma unroll
        for (int ks = 0; ks < 8; ++ks)
            bq[ks] = qp[(ks * 2 + hi) * 32 + li];
    }

    f32x16 acc[4];
    #pragma unroll
    for (int d = 0; d < 4; ++d) acc[d] = (f32x16)(0.0f);
    float mrow = -3.0e38f, srow = 0.0f;

    stageKV(ck_of(0), smem);
    stageKV(ck_of(1), smem + 65536);
    asm volatile("s_waitcnt vmcnt(8)");     // S(0) complete, S(1) in flight
    __builtin_amdgcn_s_barrier();

    for (int t = 0; t < NCH; ++t) {
        char* base = smem + (t & 1) * 65536;
        const short8* ldsK = (const short8*)base;
        const short8* ldsV = (const short8*)(base + 32768);

        #pragma unroll
        for (int pp = 0; pp < 2; ++pp) {
            const int panel = kp + 2 * pp;

            // ---- S^T = K.Q ----
            f32x16 st = (f32x16)(0.0f);
            __builtin_amdgcn_s_setprio(1);
            #pragma unroll
            for (int ks = 0; ks < 8; ++ks) {
                short8 kf = ldsK[panel * 512 + (ks * 2 + hi) * 32 + li];
                st = __builtin_amdgcn_mfma_f32_32x32x16_bf16(kf, bq[ks], st, 0, 0, 0);
            }
            __builtin_amdgcn_s_setprio(0);

            // ---- online softmax (lane-local) ----
            float mx[8];
            #pragma unroll
            for (int r = 0; r < 8; ++r) mx[r] = fmaxf(st[r], st[r + 8]);
            #pragma unroll
            for (int w = 4; w >= 1; w >>= 1)
                #pragma unroll
                for (int r = 0; r < w; ++r) mx[r] = fmaxf(mx[r], mx[r + w]);
            float pmax = fmaxf(mx[0], __shfl_xor(mx[0], 32));

            if (!__all(pmax - mrow <= THR)) {
                float mn  = fmaxf(mrow, pmax);
                float scl = __expf(mrow - mn);
                srow *= scl;
                #pragma unroll
                for (int d = 0; d < 4; ++d)
                    #pragma unroll
                    for (int r = 0; r < 16; ++r) acc[d][r] *= scl;
                mrow = mn;
            }

            #pragma unroll
            for (int r = 0; r < 16; ++r) st[r] = __expf(st[r] - mrow);
            float sm[8];
            #pragma unroll
            for (int r = 0; r < 8; ++r) sm[r] = st[r] + st[r + 8];
            #pragma unroll
            for (int w = 4; w >= 1; w >>= 1)
                #pragma unroll
                for (int r = 0; r < w; ++r) sm[r] += sm[r + w];
            srow += sm[0] + __shfl_xor(sm[0], 32);

            // ---- PV ----
            #pragma unroll
            for (int c = 0; c < 2; ++c) {
                const int b = 8 * c;
                unsigned a0 = bfpair(st[b + 0], st[b + 1]);
                unsigned a1 = bfpair(st[b + 2], st[b + 3]);
                unsigned b0 = bfpair(st[b + 4], st[b + 5]);
                unsigned b1 = bfpair(st[b + 6], st[b + 7]);
                int2v r0 = __builtin_amdgcn_permlane32_swap((int)a0, (int)b0, false, false);
                int2v r1 = __builtin_amdgcn_permlane32_swap((int)a1, (int)b1, false, false);
                union { int w[4]; short8 v; } u;
                u.w[0] = r0[0]; u.w[1] = r1[0]; u.w[2] = r0[1]; u.w[3] = r1[1];

                const short8* vp = ldsV + (panel * 2 + c) * 256 + hi * 32 + li;
                __builtin_amdgcn_s_setprio(1);
                #pragma unroll
                for (int d = 0; d < 4; ++d) {
                    short8 vf = vp[d * 64];
                    acc[d] = __builtin_amdgcn_mfma_f32_32x32x16_bf16(vf, u.v, acc[d], 0, 0, 0);
                }
                __builtin_amdgcn_s_setprio(0);
            }
        }

        __builtin_amdgcn_s_barrier();            // all waves done reading buf
        if (t + 2 < NCH) {
            stageKV(ck_of(t + 2), base);         // refill this buffer
            asm volatile("s_waitcnt vmcnt(8)");  // S(t+1) landed, S(t+2) flying
        } else {
            asm volatile("s_waitcnt vmcnt(0)");  // epilogue drain
        }
        __builtin_amdgcn_s_barrier();            // next buffer ready for all
    }

    // ---- in-block merge over kp (2 partials per qh) ----
    auto store_partial = [&](int slot) {
        #pragma unroll
        for (int d = 0; d < 4; ++d)
            #pragma unroll
            for (int rr = 0; rr < 4; ++rr) {
                f32x4 v;
                #pragma unroll
                for (int j = 0; j < 4; ++j) v[j] = acc[d][4 * rr + j];
                *reinterpret_cast<f32x4*>(&O_lds[slot][li][d * 32 + 8 * rr + 4 * hi]) = v;
            }
        if (hi == 0) { msm(slot, 0)[li] = mrow; msm(slot, 1)[li] = srow; }
    };
    auto merge_partial = [&](int slot) {
        float mb = msm(slot, 0)[li], sb = msm(slot, 1)[li];
        float M  = fmaxf(mrow, mb);
        float ea = __expf(mrow - M), eb = __expf(mb - M);
        srow = srow * ea + sb * eb;
        mrow = M;
        #pragma unroll
        for (int d = 0; d < 4; ++d)
            #pragma unroll
            for (int rr = 0; rr < 4; ++rr) {
                f32x4 v = *reinterpret_cast<const f32x4*>(&O_lds[slot][li][d * 32 + 8 * rr + 4 * hi]);
                #pragma unroll
                for (int j = 0; j < 4; ++j)
                    acc[d][4 * rr + j] = acc[d][4 * rr + j] * ea + v[j] * eb;
            }
    };

    __syncthreads();                         // staging dead; reuse as merge space
    if (kp == 1) store_partial(qh);
    __syncthreads();
    if (kp == 0) merge_partial(qh);
    __syncthreads();
    if (kp == 0) store_partial(qh);
    __syncthreads();

    // ---- write UNNORMALIZED per-block partial (128 q x 128 d) + (M,S) ----
    #pragma unroll
    for (int u0 = 0; u0 < 4; ++u0) {
        int u  = tid + u0 * 512;           // 0..2047
        int q  = u >> 4;                   // 0..127
        int dg = (u & 15) * 8;             // 0..120
        int grp = q >> 5, qq = q & 31;
        f32x4 o0 = *reinterpret_cast<const f32x4*>(&O_lds[grp][qq][dg]);
        f32x4 o1 = *reinterpret_cast<const f32x4*>(&O_lds[grp][qq][dg + 4]);
        size_t pidx = (size_t)bid * QB + q;
        *reinterpret_cast<f32x4*>(&Opart[pidx * D_FULL + dg])     = o0;
        *reinterpret_cast<f32x4*>(&Opart[pidx * D_FULL + dg + 4]) = o1;
        if (dg == 0) { Mp[pidx] = msm(grp, 0)[qq]; Sp[pidx] = msm(grp, 1)[qq]; }
    }
}

// combine the four k-quarter partials per q-row and write final output
__global__ __launch_bounds__(256) void merge4_kernel(
    const float* __restrict__ Opart, const float* __restrict__ Mp,
    const float* __restrict__ Sp, float* __restrict__ out)
{
    int i   = blockIdx.x * 256 + threadIdx.x;   // 262144 total, 4 floats each
    int row = i >> 5;                           // 0..8191
    int dg  = (i & 31) * 4;                     // 0..124
    int qt  = row >> 7, qq = row & 127;
    size_t pidx[4];
    float m[4], s[4];
    #pragma unroll
    for (int k = 0; k < 4; ++k) {
        pidx[k] = (size_t)(qt * 4 + k) * QB + qq;
        m[k] = Mp[pidx[k]];
        s[k] = Sp[pidx[k]];
    }
    float M = fmaxf(fmaxf(m[0], m[1]), fmaxf(m[2], m[3]));
    float e[4], S = 0.0f;
    #pragma unroll
    for (int k = 0; k < 4; ++k) { e[k] = __expf(m[k] - M); S += s[k] * e[k]; }
    float inv = 1.0f / S;
    f32x4 o = (f32x4)(0.0f);
    #pragma unroll
    for (int k = 0; k < 4; ++k) {
        f32x4 a = *reinterpret_cast<const f32x4*>(&Opart[pidx[k] * D_FULL + dg]);
        #pragma unroll
        for (int j = 0; j < 4; ++j) o[j] += a[j] * e[k];
    }
    #pragma unroll
    for (int j = 0; j < 4; ++j) o[j] *= inv;
    float* dst = (dg < D_HALF)
        ? out + (size_t)row * D_HALF + dg
        : out + (size_t)N_TOK * D_HALF + (size_t)row * D_HALF + (dg - D_HALF);
    *reinterpret_cast<f32x4*>(dst) = o;
}

extern "C" void kernel_launch(void* const* d_in, const int* in_sizes, int n_in,
                              void* d_out, int out_size, void* d_ws, size_t ws_size,
                              hipStream_t stream)
{
    const float* mag   = (const float*)d_in[0];
    const float* phase = (const float*)d_in[1];
    float* out = (float*)d_out;

    char* ws = (char*)d_ws;
    __hip_bfloat16* Kf = (__hip_bfloat16*)ws;                    // 2 MB
    __hip_bfloat16* Vf = Kf + (size_t)N_TOK * D_FULL;            // 2 MB
    float* Opart = (float*)(ws + 4u * 1024 * 1024);              // 16 MB
    float* Mp    = (float*)(ws + 20u * 1024 * 1024);             // 128 KB
    float* Sp    = Mp + 32768;                                   // 128 KB

    precompute_kernel<<<(N_TOK * D_HALF + 255) / 256, 256, 0, stream>>>(mag, phase, Kf, Vf);
    attn_kernel<<<256, 512, 0, stream>>>((const short8*)Kf, (const short8*)Vf, Opart, Mp, Sp);
    merge4_kernel<<<1024, 256, 0, stream>>>(Opart, Mp, Sp, out);
}